// Round 5
// baseline (884.610 us; speedup 1.0000x reference)
//
#include <hip/hip_runtime.h>

#define BATCH   2
#define SEQ     2048
#define DMODEL  1024
#define DINNER  2048
#define NHEADS  32
#define HEADDIM 64
#define DSTATE  128
#define BLTOT   (BATCH * SEQ)          // 4096 rows
#define NCHUNK  32
#define CHUNK   64                     // SEQ / NCHUNK

// ---- workspace layout (byte offsets) --------------------------------------
#define OFF_UB   0ull                  // u bf16        4096x1024   8,388,608
#define OFF_WXZ  8388608ull            // in_proj bf16  4096x1024   8,388,608
#define OFF_WBC  16777216ull           // xpw packed    16384x2048 67,108,864
#define OFF_WOUT 83886080ull           // out_proj bf16 1024x2048   4,194,304
#define OFF_XB   88080384ull           // x bf16        4096x2048  16,777,216
#define OFF_YB   104857600ull          // y bf16        4096x2048  16,777,216
#define OFF_BC   121634816ull          // bc bf16 raw   4096x16384 134,217,728
#define OFF_SZ   255852544ull          // silu(z) bf16  4096x2048  16,777,216
#define OFF_DT   272629760ull          // dt f32        4096x32       524,288
#define OFF_XS   273154048ull          // xsum f32      4096x32       524,288
#define OFF_YR   273678336ull          // yred f32      4096x32       524,288
#define OFF_CA   274202624ull          // chunk A-prod  64x32x128 c  2,097,152
#define OFF_CS   276299776ull          // chunk state   64x32x128 c  2,097,152
#define OFF_HI   278396928ull          // chunk h_in    64x32x128 c  2,097,152
#define OFF_SS   280494080ull          // norm ss f32   4096x64      1,048,576
// total 281,542,656 B = 268.5 MB

typedef __attribute__((ext_vector_type(8))) short bf16x8;
typedef __attribute__((ext_vector_type(4))) float f32x4;

__device__ __forceinline__ float b2f(unsigned short u) {
    return __uint_as_float(((unsigned)u) << 16);
}
__device__ __forceinline__ unsigned short f2b(float f) {
    unsigned x = __float_as_uint(f);
    unsigned r = (x + 0x7fffu + ((x >> 16) & 1u)) >> 16;   // RNE
    return (unsigned short)r;
}
__device__ __forceinline__ float silu_f(float v) {
    return v / (1.0f + __expf(-v));
}
__device__ __forceinline__ float softplus_f(float v) {
    return (v > 20.0f) ? v : log1pf(__expf(v));
}

__device__ __forceinline__ void gload_lds16(const void* g, void* l) {
    __builtin_amdgcn_global_load_lds(
        (const __attribute__((address_space(1))) unsigned int*)g,
        (__attribute__((address_space(3))) unsigned int*)l, 16, 0, 0);
}

// ---------------------------------------------------------------------------
// One-shot conversions: u/ipw/opw fp32->bf16, xpw fp32->packed bf16
// (drops per-head row 512: out col c <- src row (c/512)*513 + (c%512)).
// ---------------------------------------------------------------------------
__global__ __launch_bounds__(256) void conv_all_kernel(
    const float* __restrict__ u, const float* __restrict__ ipw,
    const float* __restrict__ opw, const float* __restrict__ xpw,
    unsigned short* __restrict__ u_b, unsigned short* __restrict__ w_xz,
    unsigned short* __restrict__ w_out, unsigned short* __restrict__ w_bc) {
    long idx = (long)blockIdx.x * 256 + threadIdx.x;
    if (idx >= 2621440L) {                       // xpw pack region
        long e = (idx - 2621440L) * 4;
        long c = e >> 11, k = e & 2047;
        const float* s = xpw + ((c >> 9) * 513 + (c & 511)) * 2048 + k;
        float4 v = *(const float4*)s;
        ushort4 o = {f2b(v.x), f2b(v.y), f2b(v.z), f2b(v.w)};
        *(ushort4*)&w_bc[e] = o;
        return;
    }
    const float* src;
    unsigned short* dst;
    long i;
    if (idx < 1048576L)      { src = u;   dst = u_b;   i = idx; }
    else if (idx < 2097152L) { src = ipw; dst = w_xz;  i = idx - 1048576L; }
    else                     { src = opw; dst = w_out; i = idx - 2097152L; }
    float4 v = *(const float4*)&src[i * 4];
    ushort4 o = {f2b(v.x), f2b(v.y), f2b(v.z), f2b(v.w)};
    *(ushort4*)&dst[i * 4] = o;
}

// ---------------------------------------------------------------------------
// MFMA GEMM device body (m97 structure): C[M,N] = A[M,K]@B[N,K]^T, bf16 in.
// KTOT = row stride, KLEN = K-extent of this pass (split-K), koff = K offset.
// MODE 1: silu; x-half -> bf16 C0 + per-head row-sum -> C2; z-half -> bf16 C1.
// MODE 2: bf16 C0 + per-(row, 256-col-group) sum-of-squares atomics -> ssbuf.
// MODE 3: fp32 atomicAdd into C0 (split-K partials).
// ---------------------------------------------------------------------------
template <int KTOT, int KLEN, int MODE>
__device__ __forceinline__ void gemm_body(
    const unsigned short* __restrict__ A, const unsigned short* __restrict__ B,
    void* __restrict__ C0, void* __restrict__ C1, float* __restrict__ C2,
    float* __restrict__ ssbuf, int N, int koff) {
    __shared__ short ldsA[128 * 32];
    __shared__ short ldsB[128 * 32];
    int tid = threadIdx.x;
    int row0 = blockIdx.y * 128, col0 = blockIdx.x * 128;
    int lane = tid & 63, wave = tid >> 6;
    int wrow = (wave >> 1) * 64, wcol = (wave & 1) * 64;
    int m = lane & 15, quad = lane >> 4;

    f32x4 acc[4][4];
#pragma unroll
    for (int i = 0; i < 4; ++i)
#pragma unroll
        for (int j = 0; j < 4; ++j) acc[i][j] = (f32x4){0.f, 0.f, 0.f, 0.f};

    int r = tid >> 2, c8 = (tid & 3) * 8;
    const unsigned short* Ag = A + (size_t)(row0 + r) * KTOT + koff + c8;
    const unsigned short* Bg = B + (size_t)(col0 + r) * KTOT + koff + c8;
    short* la = ldsA + tid * 8;
    short* lb = ldsB + tid * 8;

    for (int k0 = 0; k0 < KLEN; k0 += 32) {
        gload_lds16(Ag + k0, la);
        gload_lds16(Ag + (size_t)64 * KTOT + k0, la + 2048);
        gload_lds16(Bg + k0, lb);
        gload_lds16(Bg + (size_t)64 * KTOT + k0, lb + 2048);
        __syncthreads();
        bf16x8 af[4], bfr[4];
#pragma unroll
        for (int i = 0; i < 4; ++i)
            af[i] = *(const bf16x8*)&ldsA[(wrow + i * 16 + m) * 32 + quad * 8];
#pragma unroll
        for (int j = 0; j < 4; ++j)
            bfr[j] = *(const bf16x8*)&ldsB[(wcol + j * 16 + m) * 32 + quad * 8];
#pragma unroll
        for (int i = 0; i < 4; ++i)
#pragma unroll
            for (int j = 0; j < 4; ++j)
                acc[i][j] = __builtin_amdgcn_mfma_f32_16x16x32_bf16(
                    af[i], bfr[j], acc[i][j], 0, 0, 0);
        __syncthreads();
    }

    // epilogue: C/D layout col=lane&15, row=quad*4+reg  [m89/m91 verified]
    if (MODE == 1) {
        bool isx = (col0 < DINNER);          // block-uniform
        if (isx) {
            int head = (col0 + wcol) >> 6;   // wave's 64 cols = one head
            float ssum[4][4];
#pragma unroll
            for (int i = 0; i < 4; ++i)
#pragma unroll
                for (int reg = 0; reg < 4; ++reg) ssum[i][reg] = 0.f;
#pragma unroll
            for (int i = 0; i < 4; ++i)
#pragma unroll
                for (int reg = 0; reg < 4; ++reg) {
                    int row = row0 + wrow + i * 16 + quad * 4 + reg;
#pragma unroll
                    for (int j = 0; j < 4; ++j) {
                        int col = col0 + wcol + j * 16 + m;
                        float s = silu_f(acc[i][j][reg]);
                        ((unsigned short*)C0)[(size_t)row * DINNER + col] = f2b(s);
                        ssum[i][reg] += s;
                    }
                }
#pragma unroll
            for (int i = 0; i < 4; ++i)
#pragma unroll
                for (int reg = 0; reg < 4; ++reg) {
                    float s = ssum[i][reg];
                    s += __shfl_xor(s, 1);
                    s += __shfl_xor(s, 2);
                    s += __shfl_xor(s, 4);
                    s += __shfl_xor(s, 8);
                    if (m == 0) {
                        int row = row0 + wrow + i * 16 + quad * 4 + reg;
                        C2[(size_t)row * NHEADS + head] = s;
                    }
                }
        } else {
#pragma unroll
            for (int i = 0; i < 4; ++i)
#pragma unroll
                for (int reg = 0; reg < 4; ++reg) {
                    int row = row0 + wrow + i * 16 + quad * 4 + reg;
#pragma unroll
                    for (int j = 0; j < 4; ++j) {
                        int col = col0 + wcol + j * 16 + m - DINNER;
                        float s = silu_f(acc[i][j][reg]);
                        ((unsigned short*)C1)[(size_t)row * DINNER + col] = f2b(s);
                    }
                }
        }
    } else if (MODE == 2) {
        int g = (col0 + wcol) >> 8;          // 256-col norm group (wave-uniform)
        float ssq[4][4];
#pragma unroll
        for (int i = 0; i < 4; ++i)
#pragma unroll
            for (int reg = 0; reg < 4; ++reg) ssq[i][reg] = 0.f;
#pragma unroll
        for (int i = 0; i < 4; ++i)
#pragma unroll
            for (int reg = 0; reg < 4; ++reg) {
                int row = row0 + wrow + i * 16 + quad * 4 + reg;
#pragma unroll
                for (int j = 0; j < 4; ++j) {
                    int col = col0 + wcol + j * 16 + m;
                    float v = acc[i][j][reg];
                    ((unsigned short*)C0)[(size_t)row * N + col] = f2b(v);
                    ssq[i][reg] += v * v;
                }
            }
#pragma unroll
        for (int i = 0; i < 4; ++i)
#pragma unroll
            for (int reg = 0; reg < 4; ++reg) {
                float s = ssq[i][reg];
                s += __shfl_xor(s, 1);
                s += __shfl_xor(s, 2);
                s += __shfl_xor(s, 4);
                s += __shfl_xor(s, 8);
                if (m == 0) {
                    int row = row0 + wrow + i * 16 + quad * 4 + reg;
                    atomicAdd(&ssbuf[(size_t)row * 64 + g], s);
                }
            }
    } else {                                  // MODE 3: split-K atomic f32
#pragma unroll
        for (int i = 0; i < 4; ++i)
#pragma unroll
            for (int reg = 0; reg < 4; ++reg) {
                int row = row0 + wrow + i * 16 + quad * 4 + reg;
#pragma unroll
                for (int j = 0; j < 4; ++j) {
                    int col = col0 + wcol + j * 16 + m;
                    atomicAdd(&((float*)C0)[(size_t)row * N + col],
                              acc[i][j][reg]);
                }
            }
    }
}

__global__ __launch_bounds__(256) void gemm_xz_kernel(
    const unsigned short* __restrict__ A, const unsigned short* __restrict__ B,
    void* C0, void* C1, float* C2) {
    gemm_body<1024, 1024, 1>(A, B, C0, C1, C2, nullptr, 4096, 0);
}
__global__ __launch_bounds__(256) void gemm_bc_kernel(
    const unsigned short* __restrict__ A, const unsigned short* __restrict__ B,
    void* C0, float* ssbuf) {
    gemm_body<2048, 2048, 2>(A, B, C0, nullptr, nullptr, ssbuf, 16384, 0);
}
__global__ __launch_bounds__(256) void gemm_out_kernel(
    const unsigned short* __restrict__ A, const unsigned short* __restrict__ B,
    void* C0) {
    gemm_body<2048, 512, 3>(A, B, C0, nullptr, nullptr, nullptr, 1024,
                            blockIdx.z * 512);
}

// ---------------------------------------------------------------------------
// dt = softplus(x @ dtw^T + bias). 16 rows/block, LDS-tiled.
// ---------------------------------------------------------------------------
__global__ __launch_bounds__(256) void dt_kernel(
    const unsigned short* __restrict__ x, const float* __restrict__ dtw,
    const float* __restrict__ dtb, float* __restrict__ dt) {
    __shared__ float xs[16][132];
    __shared__ float ws[32][132];
    int r0 = blockIdx.x * 16;
    int t = threadIdx.x;
    int lrow = t >> 4, lc8 = (t & 15) * 8;
    int lh = t >> 3, lc16 = (t & 7) * 16;
    int row = t >> 4, h0 = t & 15;
    float acc0 = 0.f, acc1 = 0.f;

    for (int kc = 0; kc < DINNER; kc += 128) {
        ushort4 a = *(const ushort4*)&x[(size_t)(r0 + lrow) * DINNER + kc + lc8];
        ushort4 b = *(const ushort4*)&x[(size_t)(r0 + lrow) * DINNER + kc + lc8 + 4];
        xs[lrow][lc8 + 0] = b2f(a.x); xs[lrow][lc8 + 1] = b2f(a.y);
        xs[lrow][lc8 + 2] = b2f(a.z); xs[lrow][lc8 + 3] = b2f(a.w);
        xs[lrow][lc8 + 4] = b2f(b.x); xs[lrow][lc8 + 5] = b2f(b.y);
        xs[lrow][lc8 + 6] = b2f(b.z); xs[lrow][lc8 + 7] = b2f(b.w);
#pragma unroll
        for (int q = 0; q < 4; ++q) {
            float4 w = *(const float4*)&dtw[(size_t)lh * DINNER + kc + lc16 + q * 4];
            *(float4*)&ws[lh][lc16 + q * 4] = w;
        }
        __syncthreads();
#pragma unroll
        for (int k = 0; k < 128; k += 4) {
            float4 xv = *(const float4*)&xs[row][k];
            float4 w0 = *(const float4*)&ws[h0][k];
            float4 w1 = *(const float4*)&ws[h0 + 16][k];
            acc0 += xv.x * w0.x + xv.y * w0.y + xv.z * w0.z + xv.w * w0.w;
            acc1 += xv.x * w1.x + xv.y * w1.y + xv.z * w1.z + xv.w * w1.w;
        }
        __syncthreads();
    }
    dt[(size_t)(r0 + row) * NHEADS + h0]      = softplus_f(acc0 + dtb[h0]);
    dt[(size_t)(r0 + row) * NHEADS + h0 + 16] = softplus_f(acc1 + dtb[h0 + 16]);
}

// ---------------------------------------------------------------------------
// Recurrence coefficients from NORMALIZED B.
// ---------------------------------------------------------------------------
__device__ __forceinline__ void coefs(
    float ar, float ai, float dtv, float xsv, float Br, float Bi,
    float& abr, float& abi, float& ur, float& ui) {
    float hd = 0.5f * dtv;
    float ztr = ar * hd, zti = ai * hd;
    float denr = 1.0f - ztr;
    float s2 = 1.0f / (denr * denr + zti * zti);
    float invr = denr * s2, invi = zti * s2;     // 1/(1-zt)
    float opr = 1.0f + ztr;
    abr = opr * invr - zti * invi;
    abi = opr * invi + zti * invr;
    float coef = dtv * xsv;
    float cr = coef * invr, ci = coef * invi;
    ur = Br * cr - Bi * ci;
    ui = Br * ci + Bi * cr;
}

// ---------------------------------------------------------------------------
// Scan pass 1: chunk summaries P = prod(abar), S = local state. Norm scale
// read from ssbuf (no per-step reduce). Grid: B*H*NCHUNK x 64 thr.
// ---------------------------------------------------------------------------
__global__ __launch_bounds__(64) void scan_pass1(
    const unsigned short* __restrict__ bc, const float* __restrict__ dt,
    const float* __restrict__ xsum, const float* __restrict__ A,
    const float* __restrict__ wB, const float* __restrict__ ssbuf,
    float2* __restrict__ cA, float2* __restrict__ cS) {
    int blk = blockIdx.x;
    int bh = blk >> 5, c = blk & (NCHUNK - 1);
    int b = bh >> 5, h = bh & 31;
    int t = threadIdx.x;                         // states n=2t, 2t+1
    float4 av = *(const float4*)&A[(h * DSTATE + 2 * t) * 2];
    float4 wv = *(const float4*)&wB[4 * t];
    int l0 = c * CHUNK;
    const unsigned short* base = bc + ((size_t)(b * SEQ + l0)) * 16384 + h * 512;
    const float* dtp = dt + (b * SEQ + l0) * NHEADS + h;
    const float* xsp = xsum + (b * SEQ + l0) * NHEADS + h;
    const float* ssp = ssbuf + (size_t)(b * SEQ + l0) * 64 + 2 * h;

    float pr0 = 1.f, pi0 = 0.f, sr0 = 0.f, si0 = 0.f;
    float pr1 = 1.f, pi1 = 0.f, sr1 = 0.f, si1 = 0.f;
    for (int l = 0; l < CHUNK; ++l) {
        uint2 bw = *(const uint2*)&base[(size_t)l * 16384 + 4 * t];
        float scale = rsqrtf(ssp[l * 64] * (1.0f / 256.0f) + 1e-6f);
        float Br0 = b2f((unsigned short)(bw.x & 0xffff)) * scale * wv.x;
        float Bi0 = b2f((unsigned short)(bw.x >> 16)) * scale * wv.y;
        float Br1 = b2f((unsigned short)(bw.y & 0xffff)) * scale * wv.z;
        float Bi1 = b2f((unsigned short)(bw.y >> 16)) * scale * wv.w;
        float dtv = dtp[l * NHEADS], xsv = xsp[l * NHEADS];
        float abr, abi, ur, ui;
        coefs(av.x, av.y, dtv, xsv, Br0, Bi0, abr, abi, ur, ui);
        float ns = abr * sr0 - abi * si0 + ur;
        float nsi = abr * si0 + abi * sr0 + ui;
        sr0 = ns; si0 = nsi;
        float np = abr * pr0 - abi * pi0;
        float npi = abr * pi0 + abi * pr0;
        pr0 = np; pi0 = npi;
        coefs(av.z, av.w, dtv, xsv, Br1, Bi1, abr, abi, ur, ui);
        ns = abr * sr1 - abi * si1 + ur;
        nsi = abr * si1 + abi * sr1 + ui;
        sr1 = ns; si1 = nsi;
        np = abr * pr1 - abi * pi1;
        npi = abr * pi1 + abi * pr1;
        pr1 = np; pi1 = npi;
    }
    size_t idx = ((size_t)bh * NCHUNK + c) * DSTATE + 2 * t;
    *(float4*)&cA[idx] = (float4){pr0, pi0, pr1, pi1};
    *(float4*)&cS[idx] = (float4){sr0, si0, sr1, si1};
}

// ---------------------------------------------------------------------------
// Fix-up: sequential composition of 32 chunk summaries per (b,h,n).
// ---------------------------------------------------------------------------
__global__ __launch_bounds__(128) void scan_fixup(
    const float2* __restrict__ cA, const float2* __restrict__ cS,
    float2* __restrict__ hin) {
    int bh = blockIdx.x;
    int n = threadIdx.x;
    float hr = 0.f, hi = 0.f;
    for (int c = 0; c < NCHUNK; ++c) {
        size_t idx = ((size_t)bh * NCHUNK + c) * DSTATE + n;
        hin[idx] = {hr, hi};
        float2 a = cA[idx];
        float2 s = cS[idx];
        float nhr = a.x * hr - a.y * hi + s.x;
        float nhi = a.x * hi + a.y * hr + s.y;
        hr = nhr; hi = nhi;
    }
}

// ---------------------------------------------------------------------------
// Scan pass 2: replay chunk from h_in, y = sum Re(Cn*h). Scales from ssbuf.
// Grid: B*H*NCHUNK x 64 thr.
// ---------------------------------------------------------------------------
__global__ __launch_bounds__(64) void scan_pass2(
    const unsigned short* __restrict__ bc, const float* __restrict__ dt,
    const float* __restrict__ xsum, const float* __restrict__ A,
    const float* __restrict__ wB, const float* __restrict__ wC,
    const float* __restrict__ ssbuf, const float2* __restrict__ hin,
    float* __restrict__ yredp) {
    int blk = blockIdx.x;
    int bh = blk >> 5, c = blk & (NCHUNK - 1);
    int b = bh >> 5, h = bh & 31;
    int t = threadIdx.x;
    float4 av = *(const float4*)&A[(h * DSTATE + 2 * t) * 2];
    float4 wbv = *(const float4*)&wB[4 * t];
    float4 wcv = *(const float4*)&wC[4 * t];
    int l0 = c * CHUNK;
    const unsigned short* base = bc + ((size_t)(b * SEQ + l0)) * 16384 + h * 512;
    const float* dtp = dt + (b * SEQ + l0) * NHEADS + h;
    const float* xsp = xsum + (b * SEQ + l0) * NHEADS + h;
    const float* ssp = ssbuf + (size_t)(b * SEQ + l0) * 64 + 2 * h;
    float* yp = yredp + (size_t)(b * SEQ + l0) * NHEADS + h;

    float4 h0v = *(const float4*)&hin[((size_t)bh * NCHUNK + c) * DSTATE + 2 * t];
    float hr0 = h0v.x, hi0 = h0v.y, hr1 = h0v.z, hi1 = h0v.w;

    for (int l = 0; l < CHUNK; ++l) {
        uint2 bw = *(const uint2*)&base[(size_t)l * 16384 + 4 * t];
        uint2 cw = *(const uint2*)&base[(size_t)l * 16384 + 256 + 4 * t];
        float sB = rsqrtf(ssp[l * 64 + 0] * (1.0f / 256.0f) + 1e-6f);
        float sC = rsqrtf(ssp[l * 64 + 1] * (1.0f / 256.0f) + 1e-6f);
        float Br0 = b2f((unsigned short)(bw.x & 0xffff)) * sB * wbv.x;
        float Bi0 = b2f((unsigned short)(bw.x >> 16)) * sB * wbv.y;
        float Br1 = b2f((unsigned short)(bw.y & 0xffff)) * sB * wbv.z;
        float Bi1 = b2f((unsigned short)(bw.y >> 16)) * sB * wbv.w;
        float Cr0 = b2f((unsigned short)(cw.x & 0xffff)) * sC * wcv.x;
        float Ci0 = b2f((unsigned short)(cw.x >> 16)) * sC * wcv.y;
        float Cr1 = b2f((unsigned short)(cw.y & 0xffff)) * sC * wcv.z;
        float Ci1 = b2f((unsigned short)(cw.y >> 16)) * sC * wcv.w;
        float dtv = dtp[l * NHEADS], xsv = xsp[l * NHEADS];
        float abr, abi, ur, ui;
        coefs(av.x, av.y, dtv, xsv, Br0, Bi0, abr, abi, ur, ui);
        float nhr = abr * hr0 - abi * hi0 + ur;
        float nhi = abr * hi0 + abi * hr0 + ui;
        hr0 = nhr; hi0 = nhi;
        coefs(av.z, av.w, dtv, xsv, Br1, Bi1, abr, abi, ur, ui);
        nhr = abr * hr1 - abi * hi1 + ur;
        nhi = abr * hi1 + abi * hr1 + ui;
        hr1 = nhr; hi1 = nhi;
        float y = Cr0 * hr0 - Ci0 * hi0 + Cr1 * hr1 - Ci1 * hi1;
#pragma unroll
        for (int off = 1; off < 64; off <<= 1) y += __shfl_xor(y, off);
        if (t == 0) yp[(size_t)l * NHEADS] = y;
    }
}

// ---------------------------------------------------------------------------
// y = x * (yred + D[h]) * silu(z); x bf16, sz bf16, y bf16.
// ---------------------------------------------------------------------------
__global__ __launch_bounds__(256) void yfuse_kernel(
    const unsigned short* __restrict__ x, const unsigned short* __restrict__ sz,
    const float* __restrict__ yredp, const float* __restrict__ Dv,
    unsigned short* __restrict__ y) {
    int i = (blockIdx.x * 256 + threadIdx.x) * 4;
    int r = i >> 11;
    int k = i & (DINNER - 1);
    int h = k >> 6;
    float yr = yredp[(size_t)r * NHEADS + h] + Dv[h];
    ushort4 xv = *(const ushort4*)&x[i];
    ushort4 zv = *(const ushort4*)&sz[i];
    ushort4 o = {f2b(b2f(xv.x) * yr * b2f(zv.x)),
                 f2b(b2f(xv.y) * yr * b2f(zv.y)),
                 f2b(b2f(xv.z) * yr * b2f(zv.z)),
                 f2b(b2f(xv.w) * yr * b2f(zv.w))};
    *(ushort4*)&y[i] = o;
}

extern "C" void kernel_launch(void* const* d_in, const int* in_sizes, int n_in,
                              void* d_out, int out_size, void* d_ws, size_t ws_size,
                              hipStream_t stream) {
    const float* u   = (const float*)d_in[0];
    const float* ipw = (const float*)d_in[1];
    const float* dtw = (const float*)d_in[2];
    const float* dtb = (const float*)d_in[3];
    const float* xpw = (const float*)d_in[4];
    const float* A   = (const float*)d_in[5];
    const float* Dv  = (const float*)d_in[6];
    const float* wB  = (const float*)d_in[7];
    const float* wC  = (const float*)d_in[8];
    const float* opw = (const float*)d_in[9];
    float* out = (float*)d_out;
    char* ws = (char*)d_ws;

    unsigned short* u_b   = (unsigned short*)(ws + OFF_UB);
    unsigned short* w_xz  = (unsigned short*)(ws + OFF_WXZ);
    unsigned short* w_bc  = (unsigned short*)(ws + OFF_WBC);
    unsigned short* w_out = (unsigned short*)(ws + OFF_WOUT);
    unsigned short* x_b   = (unsigned short*)(ws + OFF_XB);
    unsigned short* y_b   = (unsigned short*)(ws + OFF_YB);
    unsigned short* bc    = (unsigned short*)(ws + OFF_BC);
    unsigned short* sz    = (unsigned short*)(ws + OFF_SZ);
    float* dt    = (float*)(ws + OFF_DT);
    float* xsum  = (float*)(ws + OFF_XS);
    float* yredp = (float*)(ws + OFF_YR);
    float2* cA   = (float2*)(ws + OFF_CA);
    float2* cS   = (float2*)(ws + OFF_CS);
    float2* hin  = (float2*)(ws + OFF_HI);
    float* ssbuf = (float*)(ws + OFF_SS);

    // zero the atomic accumulators (ws/d_out are poisoned before every call)
    hipMemsetAsync(ssbuf, 0, (size_t)BLTOT * 64 * 4, stream);
    hipMemsetAsync(out, 0, (size_t)BLTOT * DMODEL * 4, stream);

    conv_all_kernel<<<43008, 256, 0, stream>>>(u, ipw, opw, xpw,
                                               u_b, w_xz, w_out, w_bc);

    gemm_xz_kernel<<<dim3(32, 32), 256, 0, stream>>>(u_b, w_xz, x_b, sz, xsum);
    dt_kernel<<<BLTOT / 16, 256, 0, stream>>>(x_b, dtw, dtb, dt);
    gemm_bc_kernel<<<dim3(128, 32), 256, 0, stream>>>(x_b, w_bc, bc, ssbuf);

    scan_pass1<<<BATCH * NHEADS * NCHUNK, 64, 0, stream>>>(
        bc, dt, xsum, A, wB, ssbuf, cA, cS);
    scan_fixup<<<BATCH * NHEADS, 128, 0, stream>>>(cA, cS, hin);
    scan_pass2<<<BATCH * NHEADS * NCHUNK, 64, 0, stream>>>(
        bc, dt, xsum, A, wB, wC, ssbuf, hin, yredp);

    yfuse_kernel<<<BLTOT * DINNER / 4 / 256, 256, 0, stream>>>(
        x_b, sz, yredp, Dv, y_b);
    gemm_out_kernel<<<dim3(8, 32, 4), 256, 0, stream>>>(y_b, w_out, out);
}

// Round 6
// 832.526 us; speedup vs baseline: 1.0626x; 1.0626x over previous
//
#include <hip/hip_runtime.h>

#define BATCH   2
#define SEQ     2048
#define DMODEL  1024
#define DINNER  2048
#define NHEADS  32
#define HEADDIM 64
#define DSTATE  128
#define BLTOT   (BATCH * SEQ)          // 4096 rows
#define NCHUNK  32
#define CHUNK   64                     // SEQ / NCHUNK

// ---- workspace layout (byte offsets) --------------------------------------
#define OFF_UB   0ull                  // u bf16        4096x1024   8,388,608
#define OFF_WXZ  8388608ull            // in_proj bf16  4096x1024   8,388,608
#define OFF_WBC  16777216ull           // xpw packed    16384x2048 67,108,864
#define OFF_WOUT 83886080ull           // out_proj bf16 1024x2048   4,194,304
#define OFF_XB   88080384ull           // x bf16        4096x2048  16,777,216
#define OFF_YB   104857600ull          // y bf16        4096x2048  16,777,216
#define OFF_BC   121634816ull          // bc_t bf16 (h,row,512)     134,217,728
#define OFF_SZ   255852544ull          // silu(z) bf16  4096x2048  16,777,216
#define OFF_DT   272629760ull          // dt f32        4096x32       524,288
#define OFF_XS   273154048ull          // xsum f32      4096x32       524,288
#define OFF_YR   273678336ull          // yred f32      4096x32       524,288
#define OFF_CA   274202624ull          // chunk A-prod  64x32x128 c  2,097,152
#define OFF_CS   276299776ull          // chunk state   64x32x128 c  2,097,152
#define OFF_HI   278396928ull          // chunk h_in    64x32x128 c  2,097,152
#define OFF_SS   280494080ull          // norm ss f32   32x4096x2    1,048,576
#define OFF_P0   281542656ull          // out partial 0 f32         16,777,216
#define OFF_P1   298319872ull          // out partial 1 f32         16,777,216
// total 315,097,088 B = 300.5 MB (round-0 used 337.6 MB OK)

typedef __attribute__((ext_vector_type(8))) short bf16x8;
typedef __attribute__((ext_vector_type(4))) float f32x4;

__device__ __forceinline__ float b2f(unsigned short u) {
    return __uint_as_float(((unsigned)u) << 16);
}
__device__ __forceinline__ unsigned short f2b(float f) {
    unsigned x = __float_as_uint(f);
    unsigned r = (x + 0x7fffu + ((x >> 16) & 1u)) >> 16;   // RNE
    return (unsigned short)r;
}
__device__ __forceinline__ float silu_f(float v) {
    return v / (1.0f + __expf(-v));
}
__device__ __forceinline__ float softplus_f(float v) {
    return (v > 20.0f) ? v : log1pf(__expf(v));
}

__device__ __forceinline__ void gload_lds16(const void* g, void* l) {
    __builtin_amdgcn_global_load_lds(
        (const __attribute__((address_space(1))) unsigned int*)g,
        (__attribute__((address_space(3))) unsigned int*)l, 16, 0, 0);
}

// ---------------------------------------------------------------------------
// One-shot conversions: u/ipw/opw fp32->bf16, xpw fp32->packed bf16
// (drops per-head row 512: out col c <- src row (c/512)*513 + (c%512)).
// ---------------------------------------------------------------------------
__global__ __launch_bounds__(256) void conv_all_kernel(
    const float* __restrict__ u, const float* __restrict__ ipw,
    const float* __restrict__ opw, const float* __restrict__ xpw,
    unsigned short* __restrict__ u_b, unsigned short* __restrict__ w_xz,
    unsigned short* __restrict__ w_out, unsigned short* __restrict__ w_bc) {
    long idx = (long)blockIdx.x * 256 + threadIdx.x;
    if (idx >= 2621440L) {                       // xpw pack region
        long e = (idx - 2621440L) * 4;
        long c = e >> 11, k = e & 2047;
        const float* s = xpw + ((c >> 9) * 513 + (c & 511)) * 2048 + k;
        float4 v = *(const float4*)s;
        ushort4 o = {f2b(v.x), f2b(v.y), f2b(v.z), f2b(v.w)};
        *(ushort4*)&w_bc[e] = o;
        return;
    }
    const float* src;
    unsigned short* dst;
    long i;
    if (idx < 1048576L)      { src = u;   dst = u_b;   i = idx; }
    else if (idx < 2097152L) { src = ipw; dst = w_xz;  i = idx - 1048576L; }
    else                     { src = opw; dst = w_out; i = idx - 2097152L; }
    float4 v = *(const float4*)&src[i * 4];
    ushort4 o = {f2b(v.x), f2b(v.y), f2b(v.z), f2b(v.w)};
    *(ushort4*)&dst[i * 4] = o;
}

// ---------------------------------------------------------------------------
// MFMA GEMM device body (m97 structure): C = A[M,KTOT]@B[N,KTOT]^T slice.
// KLEN = K-extent of this pass (split-K), koff = K offset.
// MODE 0: plain fp32 store (ld = N).
// MODE 1: silu; x-half -> bf16 C0 + per-head row-sum -> C2; z-half -> bf16 C1.
// MODE 2: bf16 store TRANSPOSED: bc_t[(h*BLTOT + row)*512 + (col&511)].
// ---------------------------------------------------------------------------
template <int KTOT, int KLEN, int MODE>
__device__ __forceinline__ void gemm_body(
    const unsigned short* __restrict__ A, const unsigned short* __restrict__ B,
    void* __restrict__ C0, void* __restrict__ C1, float* __restrict__ C2,
    int N, int koff) {
    __shared__ short ldsA[128 * 32];
    __shared__ short ldsB[128 * 32];
    int tid = threadIdx.x;
    int row0 = blockIdx.y * 128, col0 = blockIdx.x * 128;
    int lane = tid & 63, wave = tid >> 6;
    int wrow = (wave >> 1) * 64, wcol = (wave & 1) * 64;
    int m = lane & 15, quad = lane >> 4;

    f32x4 acc[4][4];
#pragma unroll
    for (int i = 0; i < 4; ++i)
#pragma unroll
        for (int j = 0; j < 4; ++j) acc[i][j] = (f32x4){0.f, 0.f, 0.f, 0.f};

    int r = tid >> 2, c8 = (tid & 3) * 8;
    const unsigned short* Ag = A + (size_t)(row0 + r) * KTOT + koff + c8;
    const unsigned short* Bg = B + (size_t)(col0 + r) * KTOT + koff + c8;
    short* la = ldsA + tid * 8;
    short* lb = ldsB + tid * 8;

    for (int k0 = 0; k0 < KLEN; k0 += 32) {
        gload_lds16(Ag + k0, la);
        gload_lds16(Ag + (size_t)64 * KTOT + k0, la + 2048);
        gload_lds16(Bg + k0, lb);
        gload_lds16(Bg + (size_t)64 * KTOT + k0, lb + 2048);
        __syncthreads();
        bf16x8 af[4], bfr[4];
#pragma unroll
        for (int i = 0; i < 4; ++i)
            af[i] = *(const bf16x8*)&ldsA[(wrow + i * 16 + m) * 32 + quad * 8];
#pragma unroll
        for (int j = 0; j < 4; ++j)
            bfr[j] = *(const bf16x8*)&ldsB[(wcol + j * 16 + m) * 32 + quad * 8];
#pragma unroll
        for (int i = 0; i < 4; ++i)
#pragma unroll
            for (int j = 0; j < 4; ++j)
                acc[i][j] = __builtin_amdgcn_mfma_f32_16x16x32_bf16(
                    af[i], bfr[j], acc[i][j], 0, 0, 0);
        __syncthreads();
    }

    // epilogue: C/D layout col=lane&15, row=quad*4+reg  [m89/m91 verified]
    if (MODE == 1) {
        bool isx = (col0 < DINNER);          // block-uniform
        if (isx) {
            int head = (col0 + wcol) >> 6;   // wave's 64 cols = one head
            float ssum[4][4];
#pragma unroll
            for (int i = 0; i < 4; ++i)
#pragma unroll
                for (int reg = 0; reg < 4; ++reg) ssum[i][reg] = 0.f;
#pragma unroll
            for (int i = 0; i < 4; ++i)
#pragma unroll
                for (int reg = 0; reg < 4; ++reg) {
                    int row = row0 + wrow + i * 16 + quad * 4 + reg;
#pragma unroll
                    for (int j = 0; j < 4; ++j) {
                        int col = col0 + wcol + j * 16 + m;
                        float s = silu_f(acc[i][j][reg]);
                        ((unsigned short*)C0)[(size_t)row * DINNER + col] = f2b(s);
                        ssum[i][reg] += s;
                    }
                }
#pragma unroll
            for (int i = 0; i < 4; ++i)
#pragma unroll
                for (int reg = 0; reg < 4; ++reg) {
                    float s = ssum[i][reg];
                    s += __shfl_xor(s, 1);
                    s += __shfl_xor(s, 2);
                    s += __shfl_xor(s, 4);
                    s += __shfl_xor(s, 8);
                    if (m == 0) {
                        int row = row0 + wrow + i * 16 + quad * 4 + reg;
                        C2[(size_t)row * NHEADS + head] = s;
                    }
                }
        } else {
#pragma unroll
            for (int i = 0; i < 4; ++i)
#pragma unroll
                for (int reg = 0; reg < 4; ++reg) {
                    int row = row0 + wrow + i * 16 + quad * 4 + reg;
#pragma unroll
                    for (int j = 0; j < 4; ++j) {
                        int col = col0 + wcol + j * 16 + m - DINNER;
                        float s = silu_f(acc[i][j][reg]);
                        ((unsigned short*)C1)[(size_t)row * DINNER + col] = f2b(s);
                    }
                }
        }
    } else if (MODE == 2) {
        int hH = (col0 + wcol) >> 9;               // head (wave-uniform)
        int w0 = (col0 + wcol) & 511;              // base within-group offset
#pragma unroll
        for (int i = 0; i < 4; ++i)
#pragma unroll
            for (int reg = 0; reg < 4; ++reg) {
                int row = row0 + wrow + i * 16 + quad * 4 + reg;
                unsigned short* dst =
                    (unsigned short*)C0 + ((size_t)hH * BLTOT + row) * 512 + w0;
#pragma unroll
                for (int j = 0; j < 4; ++j)
                    dst[j * 16 + m] = f2b(acc[i][j][reg]);
            }
    } else {
#pragma unroll
        for (int i = 0; i < 4; ++i)
#pragma unroll
            for (int reg = 0; reg < 4; ++reg) {
                int row = row0 + wrow + i * 16 + quad * 4 + reg;
#pragma unroll
                for (int j = 0; j < 4; ++j) {
                    int col = col0 + wcol + j * 16 + m;
                    ((float*)C0)[(size_t)row * N + col] = acc[i][j][reg];
                }
            }
    }
}

__global__ __launch_bounds__(256) void gemm_xz_kernel(
    const unsigned short* __restrict__ A, const unsigned short* __restrict__ B,
    void* C0, void* C1, float* C2) {
    gemm_body<1024, 1024, 1>(A, B, C0, C1, C2, 4096, 0);
}
__global__ __launch_bounds__(256) void gemm_bc_kernel(
    const unsigned short* __restrict__ A, const unsigned short* __restrict__ B,
    void* C0) {
    gemm_body<2048, 2048, 2>(A, B, C0, nullptr, nullptr, 16384, 0);
}
__global__ __launch_bounds__(256) void gemm_out_kernel(
    const unsigned short* __restrict__ A, const unsigned short* __restrict__ B,
    float* P0, float* P1) {
    float* dst = blockIdx.z ? P1 : P0;
    gemm_body<2048, 1024, 0>(A, B, dst, nullptr, nullptr, 1024,
                             blockIdx.z * 1024);
}

// out = p0 + p1 (split-K combine), float4
__global__ __launch_bounds__(256) void yout_reduce_kernel(
    const float* __restrict__ p0, const float* __restrict__ p1,
    float* __restrict__ out) {
    int i = (blockIdx.x * 256 + threadIdx.x) * 4;
    float4 a = *(const float4*)&p0[i];
    float4 b = *(const float4*)&p1[i];
    float4 o = {a.x + b.x, a.y + b.y, a.z + b.z, a.w + b.w};
    *(float4*)&out[i] = o;
}

// ---------------------------------------------------------------------------
// dt = softplus(x @ dtw^T + bias). 8 rows/block, one thread per (row, head).
// xs broadcast-free (row-uniform per wave-half); ws float4 4-way conflict ok.
// ---------------------------------------------------------------------------
__global__ __launch_bounds__(256) void dt_kernel(
    const unsigned short* __restrict__ x, const float* __restrict__ dtw,
    const float* __restrict__ dtb, float* __restrict__ dt) {
    __shared__ float xs[8][132];
    __shared__ float ws[32][132];
    int r0 = blockIdx.x * 8;
    int t = threadIdx.x;
    int lrow = t >> 5, lc4 = (t & 31) * 4;   // x staging: 4 elems/thread
    int lh = t >> 3, lc16 = (t & 7) * 16;    // w staging: 16 elems/thread
    int row = t >> 5, h = t & 31;            // compute mapping
    float acc = 0.f;

    for (int kc = 0; kc < DINNER; kc += 128) {
        ushort4 a = *(const ushort4*)&x[(size_t)(r0 + lrow) * DINNER + kc + lc4];
        xs[lrow][lc4 + 0] = b2f(a.x); xs[lrow][lc4 + 1] = b2f(a.y);
        xs[lrow][lc4 + 2] = b2f(a.z); xs[lrow][lc4 + 3] = b2f(a.w);
#pragma unroll
        for (int q = 0; q < 4; ++q) {
            float4 w = *(const float4*)&dtw[(size_t)lh * DINNER + kc + lc16 + q * 4];
            *(float4*)&ws[lh][lc16 + q * 4] = w;
        }
        __syncthreads();
#pragma unroll
        for (int k = 0; k < 128; k += 4) {
            float4 xv = *(const float4*)&xs[row][k];
            float4 wv = *(const float4*)&ws[h][k];
            acc += xv.x * wv.x + xv.y * wv.y + xv.z * wv.z + xv.w * wv.w;
        }
        __syncthreads();
    }
    dt[(size_t)(r0 + row) * NHEADS + h] = softplus_f(acc + dtb[h]);
}

// ---------------------------------------------------------------------------
// ss over bc_t: one wave per (h,row) pair; lanes 0-31 -> B group, 32-63 -> C.
// Each lane: 8 elems (16 B); 5-step xor reduce within 32-lane halves.
// ---------------------------------------------------------------------------
__global__ __launch_bounds__(256) void ss_kernel(
    const unsigned short* __restrict__ bct, float* __restrict__ ss) {
    int wgid = blockIdx.x * 4 + (threadIdx.x >> 6);   // h*BLTOT + row
    int lane = threadIdx.x & 63;
    const unsigned short* p = bct + (size_t)wgid * 512 + lane * 8;
    ushort4 a = *(const ushort4*)p;
    ushort4 b = *(const ushort4*)(p + 4);
    float f0 = b2f(a.x), f1 = b2f(a.y), f2 = b2f(a.z), f3 = b2f(a.w);
    float f4 = b2f(b.x), f5 = b2f(b.y), f6 = b2f(b.z), f7 = b2f(b.w);
    float s = f0 * f0 + f1 * f1 + f2 * f2 + f3 * f3 +
              f4 * f4 + f5 * f5 + f6 * f6 + f7 * f7;
    s += __shfl_xor(s, 1);
    s += __shfl_xor(s, 2);
    s += __shfl_xor(s, 4);
    s += __shfl_xor(s, 8);
    s += __shfl_xor(s, 16);
    if ((lane & 31) == 0) ss[(size_t)wgid * 2 + (lane >> 5)] = s;
}

// ---------------------------------------------------------------------------
// Recurrence coefficients from NORMALIZED B.
// ---------------------------------------------------------------------------
__device__ __forceinline__ void coefs(
    float ar, float ai, float dtv, float xsv, float Br, float Bi,
    float& abr, float& abi, float& ur, float& ui) {
    float hd = 0.5f * dtv;
    float ztr = ar * hd, zti = ai * hd;
    float denr = 1.0f - ztr;
    float s2 = 1.0f / (denr * denr + zti * zti);
    float invr = denr * s2, invi = zti * s2;     // 1/(1-zt)
    float opr = 1.0f + ztr;
    abr = opr * invr - zti * invi;
    abi = opr * invi + zti * invr;
    float coef = dtv * xsv;
    float cr = coef * invr, ci = coef * invi;
    ur = Br * cr - Bi * ci;
    ui = Br * ci + Bi * cr;
}

// ---------------------------------------------------------------------------
// Scan pass 1: chunk summaries P = prod(abar), S = local state, from bc_t
// (sequential 1 KB rows) + precomputed ss. Grid: B*H*NCHUNK x 64 thr.
// ---------------------------------------------------------------------------
__global__ __launch_bounds__(64) void scan_pass1(
    const unsigned short* __restrict__ bct, const float* __restrict__ dt,
    const float* __restrict__ xsum, const float* __restrict__ A,
    const float* __restrict__ wB, const float* __restrict__ ss,
    float2* __restrict__ cA, float2* __restrict__ cS) {
    int blk = blockIdx.x;
    int bh = blk >> 5, c = blk & (NCHUNK - 1);
    int b = bh >> 5, h = bh & 31;
    int t = threadIdx.x;                         // states n=2t, 2t+1
    float4 av = *(const float4*)&A[(h * DSTATE + 2 * t) * 2];
    float4 wv = *(const float4*)&wB[4 * t];
    int l0 = c * CHUNK;
    size_t rbase = (size_t)h * BLTOT + b * SEQ + l0;
    const unsigned short* base = bct + rbase * 512;
    const float* ssp = ss + rbase * 2;
    const float* dtp = dt + (b * SEQ + l0) * NHEADS + h;
    const float* xsp = xsum + (b * SEQ + l0) * NHEADS + h;

    float pr0 = 1.f, pi0 = 0.f, sr0 = 0.f, si0 = 0.f;
    float pr1 = 1.f, pi1 = 0.f, sr1 = 0.f, si1 = 0.f;
    for (int l = 0; l < CHUNK; ++l) {
        uint2 bw = *(const uint2*)&base[(size_t)l * 512 + 4 * t];
        float scale = rsqrtf(ssp[l * 2] * (1.0f / 256.0f) + 1e-6f);
        float Br0 = b2f((unsigned short)(bw.x & 0xffff)) * scale * wv.x;
        float Bi0 = b2f((unsigned short)(bw.x >> 16)) * scale * wv.y;
        float Br1 = b2f((unsigned short)(bw.y & 0xffff)) * scale * wv.z;
        float Bi1 = b2f((unsigned short)(bw.y >> 16)) * scale * wv.w;
        float dtv = dtp[l * NHEADS], xsv = xsp[l * NHEADS];
        float abr, abi, ur, ui;
        coefs(av.x, av.y, dtv, xsv, Br0, Bi0, abr, abi, ur, ui);
        float ns = abr * sr0 - abi * si0 + ur;
        float nsi = abr * si0 + abi * sr0 + ui;
        sr0 = ns; si0 = nsi;
        float np = abr * pr0 - abi * pi0;
        float npi = abr * pi0 + abi * pr0;
        pr0 = np; pi0 = npi;
        coefs(av.z, av.w, dtv, xsv, Br1, Bi1, abr, abi, ur, ui);
        ns = abr * sr1 - abi * si1 + ur;
        nsi = abr * si1 + abi * sr1 + ui;
        sr1 = ns; si1 = nsi;
        np = abr * pr1 - abi * pi1;
        npi = abr * pi1 + abi * pr1;
        pr1 = np; pi1 = npi;
    }
    size_t idx = ((size_t)bh * NCHUNK + c) * DSTATE + 2 * t;
    *(float4*)&cA[idx] = (float4){pr0, pi0, pr1, pi1};
    *(float4*)&cS[idx] = (float4){sr0, si0, sr1, si1};
}

// ---------------------------------------------------------------------------
// Fix-up: sequential composition of 32 chunk summaries per (b,h,n).
// ---------------------------------------------------------------------------
__global__ __launch_bounds__(128) void scan_fixup(
    const float2* __restrict__ cA, const float2* __restrict__ cS,
    float2* __restrict__ hin) {
    int bh = blockIdx.x;
    int n = threadIdx.x;
    float hr = 0.f, hi = 0.f;
    for (int c = 0; c < NCHUNK; ++c) {
        size_t idx = ((size_t)bh * NCHUNK + c) * DSTATE + n;
        hin[idx] = {hr, hi};
        float2 a = cA[idx];
        float2 s = cS[idx];
        float nhr = a.x * hr - a.y * hi + s.x;
        float nhi = a.x * hi + a.y * hr + s.y;
        hr = nhr; hi = nhi;
    }
}

// ---------------------------------------------------------------------------
// Scan pass 2: replay chunk from h_in, y = sum Re(Cn*h). bc_t + ss reads.
// Grid: B*H*NCHUNK x 64 thr.
// ---------------------------------------------------------------------------
__global__ __launch_bounds__(64) void scan_pass2(
    const unsigned short* __restrict__ bct, const float* __restrict__ dt,
    const float* __restrict__ xsum, const float* __restrict__ A,
    const float* __restrict__ wB, const float* __restrict__ wC,
    const float* __restrict__ ss, const float2* __restrict__ hin,
    float* __restrict__ yredp) {
    int blk = blockIdx.x;
    int bh = blk >> 5, c = blk & (NCHUNK - 1);
    int b = bh >> 5, h = bh & 31;
    int t = threadIdx.x;
    float4 av = *(const float4*)&A[(h * DSTATE + 2 * t) * 2];
    float4 wbv = *(const float4*)&wB[4 * t];
    float4 wcv = *(const float4*)&wC[4 * t];
    int l0 = c * CHUNK;
    size_t rbase = (size_t)h * BLTOT + b * SEQ + l0;
    const unsigned short* base = bct + rbase * 512;
    const float* ssp = ss + rbase * 2;
    const float* dtp = dt + (b * SEQ + l0) * NHEADS + h;
    const float* xsp = xsum + (b * SEQ + l0) * NHEADS + h;
    float* yp = yredp + (size_t)(b * SEQ + l0) * NHEADS + h;

    float4 h0v = *(const float4*)&hin[((size_t)bh * NCHUNK + c) * DSTATE + 2 * t];
    float hr0 = h0v.x, hi0 = h0v.y, hr1 = h0v.z, hi1 = h0v.w;

    for (int l = 0; l < CHUNK; ++l) {
        uint2 bw = *(const uint2*)&base[(size_t)l * 512 + 4 * t];
        uint2 cw = *(const uint2*)&base[(size_t)l * 512 + 256 + 4 * t];
        float sB = rsqrtf(ssp[l * 2 + 0] * (1.0f / 256.0f) + 1e-6f);
        float sC = rsqrtf(ssp[l * 2 + 1] * (1.0f / 256.0f) + 1e-6f);
        float Br0 = b2f((unsigned short)(bw.x & 0xffff)) * sB * wbv.x;
        float Bi0 = b2f((unsigned short)(bw.x >> 16)) * sB * wbv.y;
        float Br1 = b2f((unsigned short)(bw.y & 0xffff)) * sB * wbv.z;
        float Bi1 = b2f((unsigned short)(bw.y >> 16)) * sB * wbv.w;
        float Cr0 = b2f((unsigned short)(cw.x & 0xffff)) * sC * wcv.x;
        float Ci0 = b2f((unsigned short)(cw.x >> 16)) * sC * wcv.y;
        float Cr1 = b2f((unsigned short)(cw.y & 0xffff)) * sC * wcv.z;
        float Ci1 = b2f((unsigned short)(cw.y >> 16)) * sC * wcv.w;
        float dtv = dtp[l * NHEADS], xsv = xsp[l * NHEADS];
        float abr, abi, ur, ui;
        coefs(av.x, av.y, dtv, xsv, Br0, Bi0, abr, abi, ur, ui);
        float nhr = abr * hr0 - abi * hi0 + ur;
        float nhi = abr * hi0 + abi * hr0 + ui;
        hr0 = nhr; hi0 = nhi;
        coefs(av.z, av.w, dtv, xsv, Br1, Bi1, abr, abi, ur, ui);
        nhr = abr * hr1 - abi * hi1 + ur;
        nhi = abr * hi1 + abi * hr1 + ui;
        hr1 = nhr; hi1 = nhi;
        float y = Cr0 * hr0 - Ci0 * hi0 + Cr1 * hr1 - Ci1 * hi1;
#pragma unroll
        for (int off = 1; off < 64; off <<= 1) y += __shfl_xor(y, off);
        if (t == 0) yp[(size_t)l * NHEADS] = y;
    }
}

// ---------------------------------------------------------------------------
// y = x * (yred + D[h]) * silu(z); x bf16, sz bf16, y bf16.
// ---------------------------------------------------------------------------
__global__ __launch_bounds__(256) void yfuse_kernel(
    const unsigned short* __restrict__ x, const unsigned short* __restrict__ sz,
    const float* __restrict__ yredp, const float* __restrict__ Dv,
    unsigned short* __restrict__ y) {
    int i = (blockIdx.x * 256 + threadIdx.x) * 4;
    int r = i >> 11;
    int k = i & (DINNER - 1);
    int h = k >> 6;
    float yr = yredp[(size_t)r * NHEADS + h] + Dv[h];
    ushort4 xv = *(const ushort4*)&x[i];
    ushort4 zv = *(const ushort4*)&sz[i];
    ushort4 o = {f2b(b2f(xv.x) * yr * b2f(zv.x)),
                 f2b(b2f(xv.y) * yr * b2f(zv.y)),
                 f2b(b2f(xv.z) * yr * b2f(zv.z)),
                 f2b(b2f(xv.w) * yr * b2f(zv.w))};
    *(ushort4*)&y[i] = o;
}

extern "C" void kernel_launch(void* const* d_in, const int* in_sizes, int n_in,
                              void* d_out, int out_size, void* d_ws, size_t ws_size,
                              hipStream_t stream) {
    const float* u   = (const float*)d_in[0];
    const float* ipw = (const float*)d_in[1];
    const float* dtw = (const float*)d_in[2];
    const float* dtb = (const float*)d_in[3];
    const float* xpw = (const float*)d_in[4];
    const float* A   = (const float*)d_in[5];
    const float* Dv  = (const float*)d_in[6];
    const float* wB  = (const float*)d_in[7];
    const float* wC  = (const float*)d_in[8];
    const float* opw = (const float*)d_in[9];
    float* out = (float*)d_out;
    char* ws = (char*)d_ws;

    unsigned short* u_b   = (unsigned short*)(ws + OFF_UB);
    unsigned short* w_xz  = (unsigned short*)(ws + OFF_WXZ);
    unsigned short* w_bc  = (unsigned short*)(ws + OFF_WBC);
    unsigned short* w_out = (unsigned short*)(ws + OFF_WOUT);
    unsigned short* x_b   = (unsigned short*)(ws + OFF_XB);
    unsigned short* y_b   = (unsigned short*)(ws + OFF_YB);
    unsigned short* bct   = (unsigned short*)(ws + OFF_BC);
    unsigned short* sz    = (unsigned short*)(ws + OFF_SZ);
    float* dt    = (float*)(ws + OFF_DT);
    float* xsum  = (float*)(ws + OFF_XS);
    float* yredp = (float*)(ws + OFF_YR);
    float2* cA   = (float2*)(ws + OFF_CA);
    float2* cS   = (float2*)(ws + OFF_CS);
    float2* hin  = (float2*)(ws + OFF_HI);
    float* ssbuf = (float*)(ws + OFF_SS);
    float* p0    = (float*)(ws + OFF_P0);
    float* p1    = (float*)(ws + OFF_P1);

    conv_all_kernel<<<43008, 256, 0, stream>>>(u, ipw, opw, xpw,
                                               u_b, w_xz, w_out, w_bc);

    gemm_xz_kernel<<<dim3(32, 32), 256, 0, stream>>>(u_b, w_xz, x_b, sz, xsum);
    dt_kernel<<<BLTOT / 8, 256, 0, stream>>>(x_b, dtw, dtb, dt);
    gemm_bc_kernel<<<dim3(128, 32), 256, 0, stream>>>(x_b, w_bc, bct);
    ss_kernel<<<NHEADS * BLTOT / 4, 256, 0, stream>>>(bct, ssbuf);

    scan_pass1<<<BATCH * NHEADS * NCHUNK, 64, 0, stream>>>(
        bct, dt, xsum, A, wB, ssbuf, cA, cS);
    scan_fixup<<<BATCH * NHEADS, 128, 0, stream>>>(cA, cS, hin);
    scan_pass2<<<BATCH * NHEADS * NCHUNK, 64, 0, stream>>>(
        bct, dt, xsum, A, wB, wC, ssbuf, hin, yredp);

    yfuse_kernel<<<BLTOT * DINNER / 4 / 256, 256, 0, stream>>>(
        x_b, sz, yredp, Dv, y_b);
    gemm_out_kernel<<<dim3(8, 32, 2), 256, 0, stream>>>(y_b, w_out, p0, p1);
    yout_reduce_kernel<<<BLTOT * DMODEL / 4 / 256, 256, 0, stream>>>(p0, p1, out);
}

// Round 7
// 789.193 us; speedup vs baseline: 1.1209x; 1.0549x over previous
//
#include <hip/hip_runtime.h>

#define BATCH   2
#define SEQ     2048
#define DMODEL  1024
#define DINNER  2048
#define NHEADS  32
#define HEADDIM 64
#define DSTATE  128
#define BLTOT   (BATCH * SEQ)          // 4096 rows
#define NCHUNK  32
#define CHUNK   64                     // SEQ / NCHUNK

// ---- workspace layout (byte offsets) --------------------------------------
#define OFF_UB   0ull                  // u bf16        4096x1024   8,388,608
#define OFF_WXZ  8388608ull            // in_proj bf16  4096x1024   8,388,608
#define OFF_WBC  16777216ull           // xpw packed    16384x2048 67,108,864
#define OFF_WOUT 83886080ull           // out_proj bf16 1024x2048   4,194,304
#define OFF_XB   88080384ull           // x bf16        4096x2048  16,777,216
#define OFF_YB   104857600ull          // y bf16        4096x2048  16,777,216
#define OFF_BC   121634816ull          // bc_t bf16 (h,row,512)     134,217,728
#define OFF_SZ   255852544ull          // silu(z) bf16  4096x2048  16,777,216
#define OFF_DT   272629760ull          // dt f32        4096x32       524,288
#define OFF_XS   273154048ull          // xsum f32      4096x32       524,288
#define OFF_CA   274202624ull          // chunk A-prod  64x32x128 c  2,097,152
#define OFF_CS   276299776ull          // chunk state   64x32x128 c  2,097,152
#define OFF_HI   278396928ull          // chunk h_in    64x32x128 c  2,097,152
#define OFF_SS   280494080ull          // norm scale f32 32x4096x2   1,048,576
#define OFF_P0   281542656ull          // out partial 0 f32         16,777,216
#define OFF_P1   298319872ull          // out partial 1 f32         16,777,216
// total 315,097,088 B = 300.5 MB

typedef __attribute__((ext_vector_type(8))) short bf16x8;
typedef __attribute__((ext_vector_type(4))) float f32x4;

__device__ __forceinline__ float b2f(unsigned short u) {
    return __uint_as_float(((unsigned)u) << 16);
}
__device__ __forceinline__ unsigned short f2b(float f) {
    unsigned x = __float_as_uint(f);
    unsigned r = (x + 0x7fffu + ((x >> 16) & 1u)) >> 16;   // RNE
    return (unsigned short)r;
}
__device__ __forceinline__ float silu_f(float v) {
    return v / (1.0f + __expf(-v));
}
__device__ __forceinline__ float softplus_f(float v) {
    return (v > 20.0f) ? v : log1pf(__expf(v));
}

__device__ __forceinline__ void gload_lds16(const void* g, void* l) {
    __builtin_amdgcn_global_load_lds(
        (const __attribute__((address_space(1))) unsigned int*)g,
        (__attribute__((address_space(3))) unsigned int*)l, 16, 0, 0);
}

// ---------------------------------------------------------------------------
// One-shot conversions: u/ipw/opw fp32->bf16, xpw fp32->packed bf16
// (drops per-head row 512: out col c <- src row (c/512)*513 + (c%512)).
// ---------------------------------------------------------------------------
__global__ __launch_bounds__(256) void conv_all_kernel(
    const float* __restrict__ u, const float* __restrict__ ipw,
    const float* __restrict__ opw, const float* __restrict__ xpw,
    unsigned short* __restrict__ u_b, unsigned short* __restrict__ w_xz,
    unsigned short* __restrict__ w_out, unsigned short* __restrict__ w_bc) {
    long idx = (long)blockIdx.x * 256 + threadIdx.x;
    if (idx >= 2621440L) {                       // xpw pack region
        long e = (idx - 2621440L) * 4;
        long c = e >> 11, k = e & 2047;
        const float* s = xpw + ((c >> 9) * 513 + (c & 511)) * 2048 + k;
        float4 v = *(const float4*)s;
        ushort4 o = {f2b(v.x), f2b(v.y), f2b(v.z), f2b(v.w)};
        *(ushort4*)&w_bc[e] = o;
        return;
    }
    const float* src;
    unsigned short* dst;
    long i;
    if (idx < 1048576L)      { src = u;   dst = u_b;   i = idx; }
    else if (idx < 2097152L) { src = ipw; dst = w_xz;  i = idx - 1048576L; }
    else                     { src = opw; dst = w_out; i = idx - 2097152L; }
    float4 v = *(const float4*)&src[i * 4];
    ushort4 o = {f2b(v.x), f2b(v.y), f2b(v.z), f2b(v.w)};
    *(ushort4*)&dst[i * 4] = o;
}

// ---------------------------------------------------------------------------
// MFMA GEMM device body, BK=64 variant: C = A[M,KTOT]@B[N,KTOT]^T slice.
// Two 128x32 LDS panels per operand (32 KB total); 32 MFMA per barrier pair.
// Panel addressing keeps the m97 wave-uniform lane*16B staging pattern and
// the per-panel fragment layout identical to BK=32.
// MODE 0: plain fp32 store (ld = N).
// MODE 1: silu; x-half -> bf16 C0 + per-head row-sum -> C2; z-half -> bf16 C1.
// MODE 2: bf16 store TRANSPOSED: bc_t[(h*BLTOT + row)*512 + (col&511)].
// ---------------------------------------------------------------------------
template <int KTOT, int KLEN, int MODE>
__device__ __forceinline__ void gemm_body(
    const unsigned short* __restrict__ A, const unsigned short* __restrict__ B,
    void* __restrict__ C0, void* __restrict__ C1, float* __restrict__ C2,
    int N, int koff) {
    __shared__ short ldsA[128 * 64];   // 2 panels of 128x32
    __shared__ short ldsB[128 * 64];
    int tid = threadIdx.x;
    int row0 = blockIdx.y * 128, col0 = blockIdx.x * 128;
    int lane = tid & 63, wave = tid >> 6;
    int wrow = (wave >> 1) * 64, wcol = (wave & 1) * 64;
    int m = lane & 15, quad = lane >> 4;

    f32x4 acc[4][4];
#pragma unroll
    for (int i = 0; i < 4; ++i)
#pragma unroll
        for (int j = 0; j < 4; ++j) acc[i][j] = (f32x4){0.f, 0.f, 0.f, 0.f};

    int r = tid >> 2, c8 = (tid & 3) * 8;
    const unsigned short* Ag = A + (size_t)(row0 + r) * KTOT + koff + c8;
    const unsigned short* Bg = B + (size_t)(col0 + r) * KTOT + koff + c8;
    short* la = ldsA + tid * 8;
    short* lb = ldsB + tid * 8;

    for (int k0 = 0; k0 < KLEN; k0 += 64) {
#pragma unroll
        for (int p = 0; p < 4; ++p) {
            size_t goff = (size_t)(p >> 1) * 64 * KTOT + (p & 1) * 32 + k0;
            int loff = (p & 1) * 4096 + (p >> 1) * 2048;   // shorts
            gload_lds16(Ag + goff, la + loff);
            gload_lds16(Bg + goff, lb + loff);
        }
        __syncthreads();
#pragma unroll
        for (int q = 0; q < 2; ++q) {
            bf16x8 af[4], bfr[4];
#pragma unroll
            for (int i = 0; i < 4; ++i)
                af[i] = *(const bf16x8*)
                    &ldsA[q * 4096 + (wrow + i * 16 + m) * 32 + quad * 8];
#pragma unroll
            for (int j = 0; j < 4; ++j)
                bfr[j] = *(const bf16x8*)
                    &ldsB[q * 4096 + (wcol + j * 16 + m) * 32 + quad * 8];
#pragma unroll
            for (int i = 0; i < 4; ++i)
#pragma unroll
                for (int j = 0; j < 4; ++j)
                    acc[i][j] = __builtin_amdgcn_mfma_f32_16x16x32_bf16(
                        af[i], bfr[j], acc[i][j], 0, 0, 0);
        }
        __syncthreads();
    }

    // epilogue: C/D layout col=lane&15, row=quad*4+reg  [m89/m91 verified]
    if (MODE == 1) {
        bool isx = (col0 < DINNER);          // block-uniform
        if (isx) {
            int head = (col0 + wcol) >> 6;   // wave's 64 cols = one head
            float ssum[4][4];
#pragma unroll
            for (int i = 0; i < 4; ++i)
#pragma unroll
                for (int reg = 0; reg < 4; ++reg) ssum[i][reg] = 0.f;
#pragma unroll
            for (int i = 0; i < 4; ++i)
#pragma unroll
                for (int reg = 0; reg < 4; ++reg) {
                    int row = row0 + wrow + i * 16 + quad * 4 + reg;
#pragma unroll
                    for (int j = 0; j < 4; ++j) {
                        int col = col0 + wcol + j * 16 + m;
                        float s = silu_f(acc[i][j][reg]);
                        ((unsigned short*)C0)[(size_t)row * DINNER + col] = f2b(s);
                        ssum[i][reg] += s;
                    }
                }
#pragma unroll
            for (int i = 0; i < 4; ++i)
#pragma unroll
                for (int reg = 0; reg < 4; ++reg) {
                    float s = ssum[i][reg];
                    s += __shfl_xor(s, 1);
                    s += __shfl_xor(s, 2);
                    s += __shfl_xor(s, 4);
                    s += __shfl_xor(s, 8);
                    if (m == 0) {
                        int row = row0 + wrow + i * 16 + quad * 4 + reg;
                        C2[(size_t)row * NHEADS + head] = s;
                    }
                }
        } else {
#pragma unroll
            for (int i = 0; i < 4; ++i)
#pragma unroll
                for (int reg = 0; reg < 4; ++reg) {
                    int row = row0 + wrow + i * 16 + quad * 4 + reg;
#pragma unroll
                    for (int j = 0; j < 4; ++j) {
                        int col = col0 + wcol + j * 16 + m - DINNER;
                        float s = silu_f(acc[i][j][reg]);
                        ((unsigned short*)C1)[(size_t)row * DINNER + col] = f2b(s);
                    }
                }
        }
    } else if (MODE == 2) {
        int hH = (col0 + wcol) >> 9;               // head (wave-uniform)
        int w0 = (col0 + wcol) & 511;              // base within-group offset
#pragma unroll
        for (int i = 0; i < 4; ++i)
#pragma unroll
            for (int reg = 0; reg < 4; ++reg) {
                int row = row0 + wrow + i * 16 + quad * 4 + reg;
                unsigned short* dst =
                    (unsigned short*)C0 + ((size_t)hH * BLTOT + row) * 512 + w0;
#pragma unroll
                for (int j = 0; j < 4; ++j)
                    dst[j * 16 + m] = f2b(acc[i][j][reg]);
            }
    } else {
#pragma unroll
        for (int i = 0; i < 4; ++i)
#pragma unroll
            for (int reg = 0; reg < 4; ++reg) {
                int row = row0 + wrow + i * 16 + quad * 4 + reg;
#pragma unroll
                for (int j = 0; j < 4; ++j) {
                    int col = col0 + wcol + j * 16 + m;
                    ((float*)C0)[(size_t)row * N + col] = acc[i][j][reg];
                }
            }
    }
}

__global__ __launch_bounds__(256) void gemm_xz_kernel(
    const unsigned short* __restrict__ A, const unsigned short* __restrict__ B,
    void* C0, void* C1, float* C2) {
    gemm_body<1024, 1024, 1>(A, B, C0, C1, C2, 4096, 0);
}
__global__ __launch_bounds__(256) void gemm_bc_kernel(
    const unsigned short* __restrict__ A, const unsigned short* __restrict__ B,
    void* C0) {
    gemm_body<2048, 2048, 2>(A, B, C0, nullptr, nullptr, 16384, 0);
}
__global__ __launch_bounds__(256) void gemm_out_kernel(
    const unsigned short* __restrict__ A, const unsigned short* __restrict__ B,
    float* P0, float* P1) {
    float* dst = blockIdx.z ? P1 : P0;
    gemm_body<2048, 1024, 0>(A, B, dst, nullptr, nullptr, 1024,
                             blockIdx.z * 1024);
}

// out = p0 + p1 (split-K combine), float4
__global__ __launch_bounds__(256) void yout_reduce_kernel(
    const float* __restrict__ p0, const float* __restrict__ p1,
    float* __restrict__ out) {
    int i = (blockIdx.x * 256 + threadIdx.x) * 4;
    float4 a = *(const float4*)&p0[i];
    float4 b = *(const float4*)&p1[i];
    float4 o = {a.x + b.x, a.y + b.y, a.z + b.z, a.w + b.w};
    *(float4*)&out[i] = o;
}

// ---------------------------------------------------------------------------
// dt = softplus(x @ dtw^T + bias). 8 rows/block, one thread per (row, head).
// ---------------------------------------------------------------------------
__global__ __launch_bounds__(256) void dt_kernel(
    const unsigned short* __restrict__ x, const float* __restrict__ dtw,
    const float* __restrict__ dtb, float* __restrict__ dt) {
    __shared__ float xs[8][132];
    __shared__ float ws[32][132];
    int r0 = blockIdx.x * 8;
    int t = threadIdx.x;
    int lrow = t >> 5, lc4 = (t & 31) * 4;   // x staging: 4 elems/thread
    int lh = t >> 3, lc16 = (t & 7) * 16;    // w staging: 16 elems/thread
    int row = t >> 5, h = t & 31;            // compute mapping
    float acc = 0.f;

    for (int kc = 0; kc < DINNER; kc += 128) {
        ushort4 a = *(const ushort4*)&x[(size_t)(r0 + lrow) * DINNER + kc + lc4];
        xs[lrow][lc4 + 0] = b2f(a.x); xs[lrow][lc4 + 1] = b2f(a.y);
        xs[lrow][lc4 + 2] = b2f(a.z); xs[lrow][lc4 + 3] = b2f(a.w);
#pragma unroll
        for (int q = 0; q < 4; ++q) {
            float4 w = *(const float4*)&dtw[(size_t)lh * DINNER + kc + lc16 + q * 4];
            *(float4*)&ws[lh][lc16 + q * 4] = w;
        }
        __syncthreads();
#pragma unroll
        for (int k = 0; k < 128; k += 4) {
            float4 xv = *(const float4*)&xs[row][k];
            float4 wv = *(const float4*)&ws[h][k];
            acc += xv.x * wv.x + xv.y * wv.y + xv.z * wv.z + xv.w * wv.w;
        }
        __syncthreads();
    }
    dt[(size_t)(r0 + row) * NHEADS + h] = softplus_f(acc + dtb[h]);
}

// ---------------------------------------------------------------------------
// Norm scales from bc_t: one wave per (h,row); lanes 0-31 -> B, 32-63 -> C.
// Stores rsqrt(mean(sq)+eps) directly (scans just multiply).
// ---------------------------------------------------------------------------
__global__ __launch_bounds__(256) void ss_kernel(
    const unsigned short* __restrict__ bct, float* __restrict__ ss) {
    int wgid = blockIdx.x * 4 + (threadIdx.x >> 6);   // h*BLTOT + row
    int lane = threadIdx.x & 63;
    const unsigned short* p = bct + (size_t)wgid * 512 + lane * 8;
    ushort4 a = *(const ushort4*)p;
    ushort4 b = *(const ushort4*)(p + 4);
    float f0 = b2f(a.x), f1 = b2f(a.y), f2 = b2f(a.z), f3 = b2f(a.w);
    float f4 = b2f(b.x), f5 = b2f(b.y), f6 = b2f(b.z), f7 = b2f(b.w);
    float s = f0 * f0 + f1 * f1 + f2 * f2 + f3 * f3 +
              f4 * f4 + f5 * f5 + f6 * f6 + f7 * f7;
    s += __shfl_xor(s, 1);
    s += __shfl_xor(s, 2);
    s += __shfl_xor(s, 4);
    s += __shfl_xor(s, 8);
    s += __shfl_xor(s, 16);
    if ((lane & 31) == 0)
        ss[(size_t)wgid * 2 + (lane >> 5)] =
            rsqrtf(s * (1.0f / 256.0f) + 1e-6f);
}

// ---------------------------------------------------------------------------
// Recurrence coefficients from NORMALIZED B.
// ---------------------------------------------------------------------------
__device__ __forceinline__ void coefs(
    float ar, float ai, float dtv, float xsv, float Br, float Bi,
    float& abr, float& abi, float& ur, float& ui) {
    float hd = 0.5f * dtv;
    float ztr = ar * hd, zti = ai * hd;
    float denr = 1.0f - ztr;
    float s2 = 1.0f / (denr * denr + zti * zti);
    float invr = denr * s2, invi = zti * s2;     // 1/(1-zt)
    float opr = 1.0f + ztr;
    abr = opr * invr - zti * invi;
    abi = opr * invi + zti * invr;
    float coef = dtv * xsv;
    float cr = coef * invr, ci = coef * invi;
    ur = Br * cr - Bi * ci;
    ui = Br * ci + Bi * cr;
}

// ---------------------------------------------------------------------------
// Scan pass 1: chunk summaries P = prod(abar), S = local state, from bc_t
// (sequential 1 KB rows) + precomputed scales. Grid: B*H*NCHUNK x 64 thr.
// ---------------------------------------------------------------------------
__global__ __launch_bounds__(64) void scan_pass1(
    const unsigned short* __restrict__ bct, const float* __restrict__ dt,
    const float* __restrict__ xsum, const float* __restrict__ A,
    const float* __restrict__ wB, const float* __restrict__ ss,
    float2* __restrict__ cA, float2* __restrict__ cS) {
    int blk = blockIdx.x;
    int bh = blk >> 5, c = blk & (NCHUNK - 1);
    int b = bh >> 5, h = bh & 31;
    int t = threadIdx.x;                         // states n=2t, 2t+1
    float4 av = *(const float4*)&A[(h * DSTATE + 2 * t) * 2];
    float4 wv = *(const float4*)&wB[4 * t];
    int l0 = c * CHUNK;
    size_t rbase = (size_t)h * BLTOT + b * SEQ + l0;
    const unsigned short* base = bct + rbase * 512;
    const float* ssp = ss + rbase * 2;
    const float* dtp = dt + (b * SEQ + l0) * NHEADS + h;
    const float* xsp = xsum + (b * SEQ + l0) * NHEADS + h;

    float pr0 = 1.f, pi0 = 0.f, sr0 = 0.f, si0 = 0.f;
    float pr1 = 1.f, pi1 = 0.f, sr1 = 0.f, si1 = 0.f;
    for (int l = 0; l < CHUNK; ++l) {
        uint2 bw = *(const uint2*)&base[(size_t)l * 512 + 4 * t];
        float scale = ssp[l * 2];
        float Br0 = b2f((unsigned short)(bw.x & 0xffff)) * scale * wv.x;
        float Bi0 = b2f((unsigned short)(bw.x >> 16)) * scale * wv.y;
        float Br1 = b2f((unsigned short)(bw.y & 0xffff)) * scale * wv.z;
        float Bi1 = b2f((unsigned short)(bw.y >> 16)) * scale * wv.w;
        float dtv = dtp[l * NHEADS], xsv = xsp[l * NHEADS];
        float abr, abi, ur, ui;
        coefs(av.x, av.y, dtv, xsv, Br0, Bi0, abr, abi, ur, ui);
        float ns = abr * sr0 - abi * si0 + ur;
        float nsi = abr * si0 + abi * sr0 + ui;
        sr0 = ns; si0 = nsi;
        float np = abr * pr0 - abi * pi0;
        float npi = abr * pi0 + abi * pr0;
        pr0 = np; pi0 = npi;
        coefs(av.z, av.w, dtv, xsv, Br1, Bi1, abr, abi, ur, ui);
        ns = abr * sr1 - abi * si1 + ur;
        nsi = abr * si1 + abi * sr1 + ui;
        sr1 = ns; si1 = nsi;
        np = abr * pr1 - abi * pi1;
        npi = abr * pi1 + abi * pr1;
        pr1 = np; pi1 = npi;
    }
    size_t idx = ((size_t)bh * NCHUNK + c) * DSTATE + 2 * t;
    *(float4*)&cA[idx] = (float4){pr0, pi0, pr1, pi1};
    *(float4*)&cS[idx] = (float4){sr0, si0, sr1, si1};
}

// ---------------------------------------------------------------------------
// Fix-up: sequential composition of 32 chunk summaries per (b,h,n).
// ---------------------------------------------------------------------------
__global__ __launch_bounds__(128) void scan_fixup(
    const float2* __restrict__ cA, const float2* __restrict__ cS,
    float2* __restrict__ hin) {
    int bh = blockIdx.x;
    int n = threadIdx.x;
    float hr = 0.f, hi = 0.f;
    for (int c = 0; c < NCHUNK; ++c) {
        size_t idx = ((size_t)bh * NCHUNK + c) * DSTATE + n;
        hin[idx] = {hr, hi};
        float2 a = cA[idx];
        float2 s = cS[idx];
        float nhr = a.x * hr - a.y * hi + s.x;
        float nhi = a.x * hi + a.y * hr + s.y;
        hr = nhr; hi = nhi;
    }
}

// ---------------------------------------------------------------------------
// Scan pass 2 + fused y epilogue: replay chunk from h_in, y = sum Re(Cn*h),
// then each lane handles one head-dim: y_b = x*(y+D)*silu(z) (bf16 store).
// Grid: B*H*NCHUNK x 64 thr.
// ---------------------------------------------------------------------------
__global__ __launch_bounds__(64) void scan_pass2(
    const unsigned short* __restrict__ bct, const float* __restrict__ dt,
    const float* __restrict__ xsum, const float* __restrict__ A,
    const float* __restrict__ wB, const float* __restrict__ wC,
    const float* __restrict__ ss, const float2* __restrict__ hin,
    const unsigned short* __restrict__ xb, const unsigned short* __restrict__ szb,
    const float* __restrict__ Dv, unsigned short* __restrict__ yb) {
    int blk = blockIdx.x;
    int bh = blk >> 5, c = blk & (NCHUNK - 1);
    int b = bh >> 5, h = bh & 31;
    int t = threadIdx.x;
    float4 av = *(const float4*)&A[(h * DSTATE + 2 * t) * 2];
    float4 wbv = *(const float4*)&wB[4 * t];
    float4 wcv = *(const float4*)&wC[4 * t];
    float Dh = Dv[h];
    int l0 = c * CHUNK;
    size_t rbase = (size_t)h * BLTOT + b * SEQ + l0;
    const unsigned short* base = bct + rbase * 512;
    const float* ssp = ss + rbase * 2;
    const float* dtp = dt + (b * SEQ + l0) * NHEADS + h;
    const float* xsp = xsum + (b * SEQ + l0) * NHEADS + h;
    size_t xoff0 = (size_t)(b * SEQ + l0) * DINNER + h * HEADDIM + t;

    float4 h0v = *(const float4*)&hin[((size_t)bh * NCHUNK + c) * DSTATE + 2 * t];
    float hr0 = h0v.x, hi0 = h0v.y, hr1 = h0v.z, hi1 = h0v.w;

    for (int l = 0; l < CHUNK; ++l) {
        uint2 bw = *(const uint2*)&base[(size_t)l * 512 + 4 * t];
        uint2 cw = *(const uint2*)&base[(size_t)l * 512 + 256 + 4 * t];
        float sB = ssp[l * 2 + 0];
        float sC = ssp[l * 2 + 1];
        float Br0 = b2f((unsigned short)(bw.x & 0xffff)) * sB * wbv.x;
        float Bi0 = b2f((unsigned short)(bw.x >> 16)) * sB * wbv.y;
        float Br1 = b2f((unsigned short)(bw.y & 0xffff)) * sB * wbv.z;
        float Bi1 = b2f((unsigned short)(bw.y >> 16)) * sB * wbv.w;
        float Cr0 = b2f((unsigned short)(cw.x & 0xffff)) * sC * wcv.x;
        float Ci0 = b2f((unsigned short)(cw.x >> 16)) * sC * wcv.y;
        float Cr1 = b2f((unsigned short)(cw.y & 0xffff)) * sC * wcv.z;
        float Ci1 = b2f((unsigned short)(cw.y >> 16)) * sC * wcv.w;
        float dtv = dtp[l * NHEADS], xsv = xsp[l * NHEADS];
        float abr, abi, ur, ui;
        coefs(av.x, av.y, dtv, xsv, Br0, Bi0, abr, abi, ur, ui);
        float nhr = abr * hr0 - abi * hi0 + ur;
        float nhi = abr * hi0 + abi * hr0 + ui;
        hr0 = nhr; hi0 = nhi;
        coefs(av.z, av.w, dtv, xsv, Br1, Bi1, abr, abi, ur, ui);
        nhr = abr * hr1 - abi * hi1 + ur;
        nhi = abr * hi1 + abi * hr1 + ui;
        hr1 = nhr; hi1 = nhi;
        float y = Cr0 * hr0 - Ci0 * hi0 + Cr1 * hr1 - Ci1 * hi1;
#pragma unroll
        for (int off = 1; off < 64; off <<= 1) y += __shfl_xor(y, off);
        // fused yfuse: lane t = head-dim t of this head, row l0+l
        size_t xo = xoff0 + (size_t)l * DINNER;
        float yr = y + Dh;
        float xv = b2f(xb[xo]);
        float zv = b2f(szb[xo]);
        yb[xo] = f2b(xv * yr * zv);
    }
}

extern "C" void kernel_launch(void* const* d_in, const int* in_sizes, int n_in,
                              void* d_out, int out_size, void* d_ws, size_t ws_size,
                              hipStream_t stream) {
    const float* u   = (const float*)d_in[0];
    const float* ipw = (const float*)d_in[1];
    const float* dtw = (const float*)d_in[2];
    const float* dtb = (const float*)d_in[3];
    const float* xpw = (const float*)d_in[4];
    const float* A   = (const float*)d_in[5];
    const float* Dv  = (const float*)d_in[6];
    const float* wB  = (const float*)d_in[7];
    const float* wC  = (const float*)d_in[8];
    const float* opw = (const float*)d_in[9];
    float* out = (float*)d_out;
    char* ws = (char*)d_ws;

    unsigned short* u_b   = (unsigned short*)(ws + OFF_UB);
    unsigned short* w_xz  = (unsigned short*)(ws + OFF_WXZ);
    unsigned short* w_bc  = (unsigned short*)(ws + OFF_WBC);
    unsigned short* w_out = (unsigned short*)(ws + OFF_WOUT);
    unsigned short* x_b   = (unsigned short*)(ws + OFF_XB);
    unsigned short* y_b   = (unsigned short*)(ws + OFF_YB);
    unsigned short* bct   = (unsigned short*)(ws + OFF_BC);
    unsigned short* sz    = (unsigned short*)(ws + OFF_SZ);
    float* dt    = (float*)(ws + OFF_DT);
    float* xsum  = (float*)(ws + OFF_XS);
    float2* cA   = (float2*)(ws + OFF_CA);
    float2* cS   = (float2*)(ws + OFF_CS);
    float2* hin  = (float2*)(ws + OFF_HI);
    float* ssbuf = (float*)(ws + OFF_SS);
    float* p0    = (float*)(ws + OFF_P0);
    float* p1    = (float*)(ws + OFF_P1);

    conv_all_kernel<<<43008, 256, 0, stream>>>(u, ipw, opw, xpw,
                                               u_b, w_xz, w_out, w_bc);

    gemm_xz_kernel<<<dim3(32, 32), 256, 0, stream>>>(u_b, w_xz, x_b, sz, xsum);
    dt_kernel<<<BLTOT / 8, 256, 0, stream>>>(x_b, dtw, dtb, dt);
    gemm_bc_kernel<<<dim3(128, 32), 256, 0, stream>>>(x_b, w_bc, bct);
    ss_kernel<<<NHEADS * BLTOT / 4, 256, 0, stream>>>(bct, ssbuf);

    scan_pass1<<<BATCH * NHEADS * NCHUNK, 64, 0, stream>>>(
        bct, dt, xsum, A, wB, ssbuf, cA, cS);
    scan_fixup<<<BATCH * NHEADS, 128, 0, stream>>>(cA, cS, hin);
    scan_pass2<<<BATCH * NHEADS * NCHUNK, 64, 0, stream>>>(
        bct, dt, xsum, A, wB, wC, ssbuf, hin, x_b, sz, Dv, y_b);

    gemm_out_kernel<<<dim3(8, 32, 2), 256, 0, stream>>>(y_b, w_out, p0, p1);
    yout_reduce_kernel<<<BLTOT * DMODEL / 4 / 256, 256, 0, stream>>>(p0, p1, out);
}